// Round 8
// baseline (605.570 us; speedup 1.0000x reference)
//
#include <hip/hip_runtime.h>
#include <hip/hip_bf16.h>
#include <hip/hip_cooperative_groups.h>
namespace cg = cooperative_groups;

#define N_NODES 30000
#define N_REL   8
#define N_EDGES 131072
#define FEAT    512
#define KTOT    4608   // 8*512 + 512
#define CAP     32

#define CONV_BLOCKS 15000
#define TR_BLOCKS   2304
#define CNT_BLOCKS  512
#define N_TILES     940    // 235 m-tiles x 4 n-tiles

typedef __attribute__((ext_vector_type(8))) __bf16 v8bf;
typedef __attribute__((ext_vector_type(4))) __bf16 v4bf;
typedef __attribute__((ext_vector_type(4))) float  v4f;
typedef __attribute__((ext_vector_type(8))) unsigned short u16x8;

// ---------- async global->LDS (16B per lane, wave-uniform LDS base) ----------
static __device__ __forceinline__ void load_lds16(const void* g, void* l) {
  __builtin_amdgcn_global_load_lds(
      (const __attribute__((address_space(1))) void*)g,
      (__attribute__((address_space(3))) void*)l, 16, 0, 0);
}

// =====================================================================
// Single cooperative kernel: zero -> (convert|transpose|count) -> aggregate
// -> GEMM, separated by grid.sync(). All phases grid-stride: correct at any
// co-resident grid size. Compute identical to the R6 multi-dispatch version.
// =====================================================================
__global__ __launch_bounds__(256, 4)
void k_all(const float* __restrict__ x, const float* __restrict__ w,
           const float* __restrict__ lw, const float* __restrict__ bias,
           const int* __restrict__ src, const int* __restrict__ dst,
           float* __restrict__ out, __bf16* __restrict__ xbf,
           __bf16* __restrict__ Wt, int* __restrict__ cnt,
           unsigned short* __restrict__ slots, __bf16* __restrict__ slabs) {
  cg::grid_group grid = cg::this_grid();
  const int tid = threadIdx.x;
  __shared__ union SM {
    struct { __bf16 As[128 * 64]; __bf16 Bs[128 * 64]; } g;
    float tr[32][33];
  } sm;

  // ---- phase 0: zero cnt ----
  for (int i = blockIdx.x * 256 + tid; i < N_REL * N_NODES; i += gridDim.x * 256)
    cnt[i] = 0;
  grid.sync();

  // ---- phase 1a: fp32 -> bf16 convert of x ----
  for (int b = blockIdx.x; b < CONV_BLOCKS; b += gridDim.x) {
    int i = b * 256 + tid;                          // 4 elems each
    float4 v = ((const float4*)x)[i];
    v4bf o;
    o[0] = (__bf16)v.x; o[1] = (__bf16)v.y; o[2] = (__bf16)v.z; o[3] = (__bf16)v.w;
    ((v4bf*)xbf)[i] = o;
  }
  // ---- phase 1b: W transpose -> Wt[n][k] ----
  for (int b = blockIdx.x; b < TR_BLOCKS; b += gridDim.x) {
    int k0 = (b % 144) * 32, n0 = (b / 144) * 32;
    int tx = tid & 31, ty = tid >> 5;               // 32 x 8
    __syncthreads();                                // protect tr reuse across iters
    #pragma unroll
    for (int q = 0; q < 4; ++q) {
      int k = k0 + ty + q * 8, n = n0 + tx;
      float v = (k < 4096) ? w[(size_t)k * 512 + n] : lw[(size_t)(k - 4096) * 512 + n];
      sm.tr[ty + q * 8][tx] = v;
    }
    __syncthreads();
    #pragma unroll
    for (int q = 0; q < 4; ++q) {
      int n = n0 + ty + q * 8, k = k0 + tx;
      Wt[(size_t)n * KTOT + k] = (__bf16)sm.tr[tx][ty + q * 8];
    }
  }
  // ---- phase 1c: bucket build, 8 edges/thread, XCD-affine rel ----
  for (int cb = blockIdx.x; cb < CNT_BLOCKS; cb += gridDim.x) {
    int rel = cb & 7;
    int q   = cb >> 3;
    int e0  = rel * N_EDGES + (q * 256 + tid) * 8;
    int4 sa = *(const int4*)(src + e0), sb = *(const int4*)(src + e0 + 4);
    int4 da = *(const int4*)(dst + e0), db = *(const int4*)(dst + e0 + 4);
    int ss[8] = {sa.x, sa.y, sa.z, sa.w, sb.x, sb.y, sb.z, sb.w};
    int dd[8] = {da.x, da.y, da.z, da.w, db.x, db.y, db.z, db.w};
    int bb[8], pp[8];
    #pragma unroll
    for (int j = 0; j < 8; ++j) {
      bb[j] = rel * N_NODES + dd[j];
      pp[j] = atomicAdd(&cnt[bb[j]], 1);
    }
    #pragma unroll
    for (int j = 0; j < 8; ++j)
      if (pp[j] < CAP) slots[(size_t)bb[j] * CAP + pp[j]] = (unsigned short)ss[j];
  }
  grid.sync();

  // ---- phase 2: aggregate, one wave per bucket, grid-stride ----
  {
    const int lane = tid & 63;
    const int gw = (blockIdx.x * 256 + tid) >> 6;
    const int nW = gridDim.x * 4;
    const __bf16* xb = xbf + (size_t)lane * 8;
    for (int b = gw; b < N_REL * N_NODES; b += nW) {
      const unsigned short* sl = slots + (size_t)b * CAP;
      u16x8 qs[4];                                  // one 64B line, up front
      qs[0] = *(const u16x8*)(sl);
      qs[1] = *(const u16x8*)(sl + 8);
      qs[2] = *(const u16x8*)(sl + 16);
      qs[3] = *(const u16x8*)(sl + 24);
      int c = cnt[b];
      int cc = c < CAP ? c : CAP;
      float acc[8] = {0.f,0.f,0.f,0.f,0.f,0.f,0.f,0.f};
      #pragma unroll
      for (int g = 0; g < 4; ++g) {
        if (cc > g * 8) {                           // wave-uniform branch
          int m = cc - g * 8;
          v8bf r[8];
          #pragma unroll
          for (int j = 0; j < 8; ++j)
            if (m > j) r[j] = *(const v8bf*)(xb + (size_t)qs[g][j] * FEAT);
          #pragma unroll
          for (int j = 0; j < 8; ++j)
            if (m > j) {
              #pragma unroll
              for (int t = 0; t < 8; ++t) acc[t] += (float)r[j][t];
            }
        }
      }
      float scale = 1.0f / (float)(c > 1 ? c : 1);
      v8bf o;
      #pragma unroll
      for (int t = 0; t < 8; ++t) o[t] = (__bf16)(acc[t] * scale);
      *(v8bf*)(slabs + (size_t)b * FEAT + lane * 8) = o;
    }
  }
  grid.sync();

  // ---- phase 3: GEMM C = A[30000,4608] @ Wt^T, 128x128 tiles, XOR-swizzled LDS ----
  {
    const int wave = tid >> 6;
    const int lane = tid & 63;
    const int lr = lane >> 3, lc = lane & 7;
    const int gcs = (lc ^ lr) * 8;                  // swizzled global chunk offset
    const int quad = lane >> 4, l15 = lane & 15;
    const int wRow = wave >> 1, wCol = wave & 1;
    const __bf16* A = slabs;

    for (int t9 = blockIdx.x; t9 < N_TILES; t9 += gridDim.x) {
      const int mBase = (t9 >> 2) * 128;
      const int nBase = (t9 & 3) * 128;

      v4f acc[4][4];
      #pragma unroll
      for (int i = 0; i < 4; ++i)
        #pragma unroll
        for (int j = 0; j < 4; ++j) acc[i][j] = (v4f){0.f, 0.f, 0.f, 0.f};

      for (int kt = 0; kt < KTOT / 64; ++kt) {
        const int kk = kt * 64;
        const __bf16* aT = A + (size_t)(kk >> 9) * ((size_t)N_NODES * FEAT) + (kk & 511);
        #pragma unroll
        for (int t = 0; t < 4; ++t) {
          int chunk = wave * 4 + t;                 // 8 rows x 64 cols per chunk
          int row = mBase + chunk * 8 + lr;
          if (row > N_NODES - 1) row = N_NODES - 1; // clamp; masked at store
          load_lds16(aT + (size_t)row * FEAT + gcs, sm.g.As + chunk * 512);
          int n = nBase + chunk * 8 + lr;
          load_lds16(Wt + (size_t)n * KTOT + kk + gcs, sm.g.Bs + chunk * 512);
        }
        __syncthreads();
        #pragma unroll
        for (int ks = 0; ks < 2; ++ks) {
          const int q = ks * 4 + quad;
          v8bf af[4], bfr[4];
          #pragma unroll
          for (int mi = 0; mi < 4; ++mi) {
            int m = wRow * 64 + mi * 16 + l15;
            af[mi] = *(const v8bf*)(sm.g.As + m * 64 + ((q ^ (m & 7)) * 8));
          }
          #pragma unroll
          for (int ni = 0; ni < 4; ++ni) {
            int n = wCol * 64 + ni * 16 + l15;
            bfr[ni] = *(const v8bf*)(sm.g.Bs + n * 64 + ((q ^ (n & 7)) * 8));
          }
          #pragma unroll
          for (int mi = 0; mi < 4; ++mi)
            #pragma unroll
            for (int ni = 0; ni < 4; ++ni)
              acc[mi][ni] = __builtin_amdgcn_mfma_f32_16x16x32_bf16(af[mi], bfr[ni], acc[mi][ni], 0, 0, 0);
        }
        __syncthreads();
      }

      // epilogue: D row = quad*4+r, col = l15 within each 16x16 tile
      #pragma unroll
      for (int ni = 0; ni < 4; ++ni) {
        int col = nBase + wCol * 64 + ni * 16 + l15;
        float bv = bias[col];
        #pragma unroll
        for (int mi = 0; mi < 4; ++mi) {
          int row0 = mBase + wRow * 64 + mi * 16 + quad * 4;
          #pragma unroll
          for (int r = 0; r < 4; ++r) {
            int row = row0 + r;
            if (row < N_NODES) {
              float v = acc[mi][ni][r] + bv;
              out[(size_t)row * FEAT + col] = fmaxf(v, 0.0f);
            }
          }
        }
      }
    }
  }
}

// =====================================================================
// Fallback kernels (only used if workspace can't hold all 9 slabs — not the
// observed configuration; kept for safety).
// =====================================================================
__global__ void k_prep(const float* __restrict__ x, const float* __restrict__ w,
                       const float* __restrict__ lw, const int* __restrict__ src,
                       const int* __restrict__ dst, __bf16* __restrict__ xbf,
                       __bf16* __restrict__ Wt, int* __restrict__ cnt,
                       unsigned short* __restrict__ slots) {
  __shared__ float t[32][33];
  const int b = blockIdx.x, tid = threadIdx.x;
  if (b < CONV_BLOCKS) {
    int i = b * 256 + tid;
    float4 v = ((const float4*)x)[i];
    v4bf o;
    o[0] = (__bf16)v.x; o[1] = (__bf16)v.y; o[2] = (__bf16)v.z; o[3] = (__bf16)v.w;
    ((v4bf*)xbf)[i] = o;
  } else if (b < CONV_BLOCKS + TR_BLOCKS) {
    int tb = b - CONV_BLOCKS;
    int k0 = (tb % 144) * 32, n0 = (tb / 144) * 32;
    int tx = tid & 31, ty = tid >> 5;
    #pragma unroll
    for (int q = 0; q < 4; ++q) {
      int k = k0 + ty + q * 8, n = n0 + tx;
      float v = (k < 4096) ? w[(size_t)k * 512 + n] : lw[(size_t)(k - 4096) * 512 + n];
      t[ty + q * 8][tx] = v;
    }
    __syncthreads();
    #pragma unroll
    for (int q = 0; q < 4; ++q) {
      int n = n0 + ty + q * 8, k = k0 + tx;
      Wt[(size_t)n * KTOT + k] = (__bf16)t[tx][ty + q * 8];
    }
  } else {
    int cb  = b - CONV_BLOCKS - TR_BLOCKS;
    int rel = cb & 7, q = cb >> 3;
    int e0  = rel * N_EDGES + (q * 256 + tid) * 8;
    int4 sa = *(const int4*)(src + e0), sb = *(const int4*)(src + e0 + 4);
    int4 da = *(const int4*)(dst + e0), db = *(const int4*)(dst + e0 + 4);
    int ss[8] = {sa.x, sa.y, sa.z, sa.w, sb.x, sb.y, sb.z, sb.w};
    int dd[8] = {da.x, da.y, da.z, da.w, db.x, db.y, db.z, db.w};
    int bb[8], pp[8];
    #pragma unroll
    for (int j = 0; j < 8; ++j) {
      bb[j] = rel * N_NODES + dd[j];
      pp[j] = atomicAdd(&cnt[bb[j]], 1);
    }
    #pragma unroll
    for (int j = 0; j < 8; ++j)
      if (pp[j] < CAP) slots[(size_t)bb[j] * CAP + pp[j]] = (unsigned short)ss[j];
  }
}

__global__ __launch_bounds__(256)
void k_aggregate(const __bf16* __restrict__ xbf, const int* __restrict__ cnt,
                 const unsigned short* __restrict__ slots,
                 __bf16* __restrict__ out, int nBuckets) {
  int w = (blockIdx.x * blockDim.x + threadIdx.x) >> 6;
  int lane = threadIdx.x & 63;
  if (w >= nBuckets) return;
  const unsigned short* sl = slots + (size_t)w * CAP;
  u16x8 qs[4];
  qs[0] = *(const u16x8*)(sl);
  qs[1] = *(const u16x8*)(sl + 8);
  qs[2] = *(const u16x8*)(sl + 16);
  qs[3] = *(const u16x8*)(sl + 24);
  int c = cnt[w];
  int cc = c < CAP ? c : CAP;
  const __bf16* xb = xbf + (size_t)lane * 8;
  float acc[8] = {0.f,0.f,0.f,0.f,0.f,0.f,0.f,0.f};
  #pragma unroll
  for (int g = 0; g < 4; ++g) {
    if (cc > g * 8) {
      int m = cc - g * 8;
      v8bf r[8];
      #pragma unroll
      for (int j = 0; j < 8; ++j)
        if (m > j) r[j] = *(const v8bf*)(xb + (size_t)qs[g][j] * FEAT);
      #pragma unroll
      for (int j = 0; j < 8; ++j)
        if (m > j) {
          #pragma unroll
          for (int t = 0; t < 8; ++t) acc[t] += (float)r[j][t];
        }
    }
  }
  float scale = 1.0f / (float)(c > 1 ? c : 1);
  v8bf o;
  #pragma unroll
  for (int t = 0; t < 8; ++t) o[t] = (__bf16)(acc[t] * scale);
  *(v8bf*)(out + (size_t)w * FEAT + lane * 8) = o;
}

template <bool ACCUM, bool FINAL>
__global__ __launch_bounds__(256, 4)
void k_gemm(const __bf16* __restrict__ A, size_t slabStride,
            const __bf16* __restrict__ Wt, int wtStride, int kTiles,
            const float* __restrict__ bias, float* __restrict__ C) {
  __shared__ __bf16 As[128 * 64];
  __shared__ __bf16 Bs[128 * 64];
  const int tid  = threadIdx.x;
  const int wave = tid >> 6;
  const int lane = tid & 63;
  const int lr = lane >> 3, lc = lane & 7;
  const int gcs = (lc ^ lr) * 8;
  const int quad = lane >> 4, l15 = lane & 15;
  const int wRow = wave >> 1, wCol = wave & 1;
  const int mtile = blockIdx.x >> 2, ntile = blockIdx.x & 3;
  if (mtile >= (N_NODES + 127) / 128) return;
  const int mBase = mtile * 128, nBase = ntile * 128;

  v4f acc[4][4];
  #pragma unroll
  for (int i = 0; i < 4; ++i)
    #pragma unroll
    for (int j = 0; j < 4; ++j) acc[i][j] = (v4f){0.f, 0.f, 0.f, 0.f};

  for (int kt = 0; kt < kTiles; ++kt) {
    const int kk = kt * 64;
    const __bf16* aT = A + (size_t)(kk >> 9) * slabStride + (kk & 511);
    #pragma unroll
    for (int t = 0; t < 4; ++t) {
      int chunk = wave * 4 + t;
      int row = mBase + chunk * 8 + lr;
      if (row > N_NODES - 1) row = N_NODES - 1;
      load_lds16(aT + (size_t)row * FEAT + gcs, As + chunk * 512);
      int n = nBase + chunk * 8 + lr;
      load_lds16(Wt + (size_t)n * wtStride + kk + gcs, Bs + chunk * 512);
    }
    __syncthreads();
    #pragma unroll
    for (int ks = 0; ks < 2; ++ks) {
      const int q = ks * 4 + quad;
      v8bf af[4], bfr[4];
      #pragma unroll
      for (int mi = 0; mi < 4; ++mi) {
        int m = wRow * 64 + mi * 16 + l15;
        af[mi] = *(const v8bf*)(As + m * 64 + ((q ^ (m & 7)) * 8));
      }
      #pragma unroll
      for (int ni = 0; ni < 4; ++ni) {
        int n = wCol * 64 + ni * 16 + l15;
        bfr[ni] = *(const v8bf*)(Bs + n * 64 + ((q ^ (n & 7)) * 8));
      }
      #pragma unroll
      for (int mi = 0; mi < 4; ++mi)
        #pragma unroll
        for (int ni = 0; ni < 4; ++ni)
          acc[mi][ni] = __builtin_amdgcn_mfma_f32_16x16x32_bf16(af[mi], bfr[ni], acc[mi][ni], 0, 0, 0);
    }
    __syncthreads();
  }
  #pragma unroll
  for (int ni = 0; ni < 4; ++ni) {
    int col = nBase + wCol * 64 + ni * 16 + l15;
    float bv = FINAL ? bias[col] : 0.0f;
    #pragma unroll
    for (int mi = 0; mi < 4; ++mi) {
      int row0 = mBase + wRow * 64 + mi * 16 + quad * 4;
      #pragma unroll
      for (int r = 0; r < 4; ++r) {
        int row = row0 + r;
        if (row < N_NODES) {
          size_t idx = (size_t)row * FEAT + col;
          float v = acc[mi][ni][r];
          if (ACCUM) v += C[idx];
          if (FINAL) { v += bv; v = fmaxf(v, 0.0f); }
          C[idx] = v;
        }
      }
    }
  }
}

extern "C" void kernel_launch(void* const* d_in, const int* in_sizes, int n_in,
                              void* d_out, int out_size, void* d_ws, size_t ws_size,
                              hipStream_t stream) {
  const float* x    = (const float*)d_in[0];
  const float* w    = (const float*)d_in[1];
  const float* lw   = (const float*)d_in[2];
  const float* bias = (const float*)d_in[3];
  const int*   src  = (const int*)d_in[4];
  const int*   dst  = (const int*)d_in[5];
  float* out = (float*)d_out;

  char* ws = (char*)d_ws;
  const size_t SLAB  = (size_t)N_NODES * FEAT;
  const size_t slabB = SLAB * 2;                            // 30.72 MB
  const size_t wtB   = (size_t)FEAT * KTOT * 2;             // 4.72 MB
  const size_t cntB  = (size_t)N_REL * N_NODES * 4;         // 0.96 MB
  const size_t slotB = (size_t)N_REL * N_NODES * CAP * 2;   // 15.36 MB
  const size_t fixedB = wtB + cntB + slotB;                 // 21.04 MB

  __bf16*         Wt     = (__bf16*)ws;
  int*            cnt    = (int*)(ws + wtB);
  unsigned short* slots  = (unsigned short*)(ws + wtB + cntB);
  __bf16*         slabs  = (__bf16*)(ws + fixedB);

  int nSlab = (int)((ws_size - fixedB) / slabB);
  if (nSlab > 9) nSlab = 9;
  int g = nSlab - 1;
  if (g > 8) g = 8;
  if (g < 1) g = 1;
  __bf16* xbf = slabs + (size_t)g * SLAB;                   // last slot = x (bf16)

  if (g == 8) {
    int maxB = 0;
    hipOccupancyMaxActiveBlocksPerMultiprocessor(&maxB, k_all, 256, 0);
    if (maxB < 1) maxB = 1;
    int gridN = maxB * 256;
    if (gridN > 1024) gridN = 1024;
    void* args[] = {(void*)&x, (void*)&w, (void*)&lw, (void*)&bias,
                    (void*)&src, (void*)&dst, (void*)&out, (void*)&xbf,
                    (void*)&Wt, (void*)&cnt, (void*)&slots, (void*)&slabs};
    hipLaunchCooperativeKernel((void*)k_all, dim3(gridN), dim3(256), args, 0, stream);
  } else {
    hipMemsetAsync(cnt, 0, cntB, stream);
    k_prep<<<CONV_BLOCKS + TR_BLOCKS + CNT_BLOCKS, 256, 0, stream>>>(
        x, w, lw, src, dst, xbf, Wt, cnt, slots);
    const int nMtiles = (N_NODES + 127) / 128;
    const int gemmGrid = nMtiles * 4;
    for (int r0 = 0; r0 < N_REL; r0 += g) {
      int gc2 = (N_REL - r0) < g ? (N_REL - r0) : g;
      k_aggregate<<<(gc2 * N_NODES) / 4, 256, 0, stream>>>(
          xbf, cnt + r0 * N_NODES, slots + (size_t)r0 * N_NODES * CAP,
          slabs, gc2 * N_NODES);
      if (r0 == 0)
        k_gemm<false, false><<<gemmGrid, 256, 0, stream>>>(
            slabs, SLAB, Wt + r0 * 512, KTOT, gc2 * 8, bias, out);
      else
        k_gemm<true, false><<<gemmGrid, 256, 0, stream>>>(
            slabs, SLAB, Wt + r0 * 512, KTOT, gc2 * 8, bias, out);
    }
    k_gemm<true, true><<<gemmGrid, 256, 0, stream>>>(xbf, SLAB, Wt + 4096, KTOT,
                                                     8, bias, out);
  }
}